// Round 2
// baseline (432.139 us; speedup 1.0000x reference)
//
#include <hip/hip_runtime.h>

#define ZDIM 4096
#define DIN  256
#define DTS  2048
#define DOUT 256
#define CDIM 65536
#define SPLIT 8
#define CHUNK (CDIM / SPLIT)   // 8192 c per chunk = 32 i-blocks of 256 j

typedef float fv4 __attribute__((ext_vector_type(4)));
typedef __bf16 bv8 __attribute__((ext_vector_type(8)));
typedef unsigned short u16;
typedef u16 uv8 __attribute__((ext_vector_type(8)));
typedef u16 uv4 __attribute__((ext_vector_type(4)));

union BC  { __bf16 b; u16 u; };
union VC8 { uv8 u; bv8 b; };

static __device__ __forceinline__ u16  f2b(float f){ BC c; c.b=(__bf16)f; return c.u; }
static __device__ __forceinline__ bv8  asb(uv8 x){ VC8 c; c.u=x; return c.b; }
static __device__ __forceinline__ uv8  pack8(fv4 a, fv4 b){
  uv8 p;
  p[0]=f2b(a[0]); p[1]=f2b(a[1]); p[2]=f2b(a[2]); p[3]=f2b(a[3]);
  p[4]=f2b(b[0]); p[5]=f2b(b[1]); p[6]=f2b(b[2]); p[7]=f2b(b[3]);
  return p;
}

// ---------------------------------------------------------------------------
// Kernel 1: Kmat[k][c] = sum_t W[k][t] * T[t][c]   (bf16 output in ws)
// memory-bound: streams 512 MB of T once (~85 us floor). Unchanged.
// ---------------------------------------------------------------------------
__global__ __launch_bounds__(512, 2) void k_wt(const float* __restrict__ W,
                                               const float* __restrict__ T,
                                               u16* __restrict__ Km) {
  __shared__ u16 Al[256 * 40];   // W tile [k][t], padded stride 40
  __shared__ u16 Bl[32 * 128];   // T tile [t][c], row-major
  const int tid  = threadIdx.x;
  const int lane = tid & 63;
  const int wave = tid >> 6;
  const int wk = (wave >> 1) * 64;
  const int wc = (wave & 1) * 64;
  const int cb = blockIdx.x * 128;
  const int ar = lane & 15, tg = lane >> 4;

  fv4 acc[4][4];
#pragma unroll
  for (int m = 0; m < 4; ++m)
#pragma unroll
    for (int n = 0; n < 4; ++n)
#pragma unroll
      for (int r = 0; r < 4; ++r) acc[m][n][r] = 0.f;

  for (int t0 = 0; t0 < DTS; t0 += 32) {
#pragma unroll
    for (int p = 0; p < 2; ++p) {
      int oct = tid + p * 512;
      int kr = oct >> 2, ts = (oct & 3) * 8;
      const float* src = W + (size_t)kr * DTS + t0 + ts;
      fv4 a = *(const fv4*)src, b = *(const fv4*)(src + 4);
      *(uv8*)&Al[kr * 40 + ts] = pack8(a, b);
    }
    {
      int tr = tid >> 4, co = (tid & 15) * 8;
      const float* src = T + (size_t)(t0 + tr) * CDIM + cb + co;
      fv4 a = *(const fv4*)src, b = *(const fv4*)(src + 4);
      *(uv8*)&Bl[tr * 128 + co] = pack8(a, b);
    }
    __syncthreads();
    bv8 af[4];
#pragma unroll
    for (int m = 0; m < 4; ++m)
      af[m] = asb(*(const uv8*)&Al[(wk + m * 16 + ar) * 40 + tg * 8]);
#pragma unroll
    for (int n = 0; n < 4; ++n) {
      uv8 bu;
#pragma unroll
      for (int e = 0; e < 8; ++e)
        bu[e] = Bl[(tg * 8 + e) * 128 + wc + n * 16 + ar];
      bv8 bf = asb(bu);
#pragma unroll
      for (int m = 0; m < 4; ++m)
        acc[m][n] = __builtin_amdgcn_mfma_f32_16x16x32_bf16(af[m], bf, acc[m][n], 0, 0, 0);
    }
    __syncthreads();
  }
#pragma unroll
  for (int m = 0; m < 4; ++m)
#pragma unroll
    for (int n = 0; n < 4; ++n)
#pragma unroll
      for (int r = 0; r < 4; ++r) {
        int kr = wk + m * 16 + tg * 4 + r;
        int cc = cb + wc + n * 16 + ar;
        Km[(size_t)kr * CDIM + cc] = f2b(acc[m][n][r]);
      }
}

// ---------------------------------------------------------------------------
// Kernel 2 (restructured): out[z,k] = sum_i x[z,i] * (sum_j Km[k,i*256+j]*x[z,j])
// A-fragments (x rows, bf16) are i-invariant -> preloaded in 128 VGPRs.
// Inner j-GEMM accumulates into aci; fold x[z,i] (f32) at each i boundary.
// Bl double-buffered, staged via global_load_lds (width 16), 1 barrier/step.
// grid 512: bid&7 = split chunk (XCD-affine), bid>>3 = z-panel of 64
// block 512 = 8 waves, wave owns 64z x 32k
// ---------------------------------------------------------------------------
__global__ __launch_bounds__(512, 2) void k_bil(const float* __restrict__ X,
                                                const u16* __restrict__ Km,
                                                float* __restrict__ P) {
  __shared__ u16 Bl[2][256 * 32];   // 2 x 16 KB, [k][32 j] unpadded (gload_lds linear)
  __shared__ float Xt[32 * 64];     // 8 KB: Xt[i][z] = X[z0+z][i0+i]
  const int tid  = threadIdx.x;
  const int lane = tid & 63;
  const int wave = tid >> 6;
  const int wkk  = wave * 32;
  const int bid  = blockIdx.x;
  const int s    = bid & 7;
  const int z0   = (bid >> 3) * 64;
  const int i0   = s * 32;
  const int cs   = s * CHUNK;
  const int ar = lane & 15, tg = lane >> 4;

  // stage Xt (one-time; small gather from L2/L3)
  for (int idx = tid; idx < 32 * 64; idx += 512) {
    int ii = idx >> 6, z = idx & 63;
    Xt[idx] = X[(size_t)(z0 + z) * DIN + i0 + ii];
  }

  // preload A-fragments: af[m][js] = bf16(x[z0+m*16+ar][js*32+tg*8 .. +8])
  uv8 af[4][8];
#pragma unroll
  for (int m = 0; m < 4; ++m) {
    const float* row = X + (size_t)(z0 + m * 16 + ar) * DIN;
#pragma unroll
    for (int js = 0; js < 8; ++js) {
      const float* src = row + js * 32 + tg * 8;
      fv4 a = *(const fv4*)src, b = *(const fv4*)(src + 4);
      af[m][js] = pack8(a, b);
    }
  }

  // B-tile stage: 16 KB via global_load_lds, 2 passes of 512 threads x 16B
#define STAGE(BUF, CBASE)                                                        \
  {                                                                              \
    _Pragma("unroll")                                                            \
    for (int p = 0; p < 2; ++p) {                                                \
      int idx = p * 512 + tid;                                                   \
      int kk = idx >> 2;                                                         \
      int jj = (idx & 3) * 8;                                                    \
      const u16* gsrc = Km + (size_t)kk * CDIM + (CBASE) + jj;                   \
      u16* ldst = &Bl[BUF][idx * 8];                                             \
      __builtin_amdgcn_global_load_lds(                                          \
          (const __attribute__((address_space(1))) void*)gsrc,                   \
          (__attribute__((address_space(3))) void*)ldst, 16, 0, 0);              \
    }                                                                            \
  }

  STAGE(0, cs)
  __syncthreads();

  fv4 mas[4][2], aci[4][2];
#pragma unroll
  for (int m = 0; m < 4; ++m)
#pragma unroll
    for (int n = 0; n < 2; ++n)
#pragma unroll
      for (int r = 0; r < 4; ++r) { mas[m][n][r] = 0.f; aci[m][n][r] = 0.f; }

  int buf = 0;
  for (int i = 0; i < 32; ++i) {
#pragma unroll
    for (int js = 0; js < 8; ++js) {
      const int st = i * 8 + js;
      if (st + 1 < 256) STAGE(buf ^ 1, cs + (st + 1) * 32)
      bv8 bf[2];
#pragma unroll
      for (int n = 0; n < 2; ++n)
        bf[n] = asb(*(const uv8*)&Bl[buf][(wkk + n * 16 + ar) * 32 + tg * 8]);
#pragma unroll
      for (int n = 0; n < 2; ++n)
#pragma unroll
        for (int m = 0; m < 4; ++m)
          aci[m][n] = __builtin_amdgcn_mfma_f32_16x16x32_bf16(asb(af[m][js]), bf[n], aci[m][n], 0, 0, 0);
      __syncthreads();
      buf ^= 1;
    }
    // fold x[z,i] (f32): mas += xi * aci ; acc rows r=0..3 <-> z = m*16+tg*4+r
#pragma unroll
    for (int m = 0; m < 4; ++m) {
      fv4 xi4 = *(const fv4*)&Xt[i * 64 + m * 16 + tg * 4];
#pragma unroll
      for (int n = 0; n < 2; ++n) {
        mas[m][n] += xi4 * aci[m][n];
#pragma unroll
        for (int r = 0; r < 4; ++r) aci[m][n][r] = 0.f;
      }
    }
  }
#undef STAGE

  float* dst = P + (size_t)s * (ZDIM * DOUT) + (size_t)z0 * DOUT;
#pragma unroll
  for (int m = 0; m < 4; ++m)
#pragma unroll
    for (int n = 0; n < 2; ++n)
#pragma unroll
      for (int r = 0; r < 4; ++r)
        dst[(size_t)(m * 16 + tg * 4 + r) * DOUT + wkk + n * 16 + ar] = mas[m][n][r];
}

// ---------------------------------------------------------------------------
// Kernel 3: out[z][k] = sum_s partial[s][z][k]
// ---------------------------------------------------------------------------
__global__ __launch_bounds__(256) void k_red(const float* __restrict__ P,
                                             float* __restrict__ O) {
  size_t idx = ((size_t)blockIdx.x * 256 + threadIdx.x) * 4;
  fv4 acc;
#pragma unroll
  for (int r = 0; r < 4; ++r) acc[r] = 0.f;
#pragma unroll
  for (int p = 0; p < SPLIT; ++p)
    acc += *(const fv4*)&P[(size_t)p * (ZDIM * DOUT) + idx];
  *(fv4*)&O[idx] = acc;
}

extern "C" void kernel_launch(void* const* d_in, const int* in_sizes, int n_in,
                              void* d_out, int out_size, void* d_ws, size_t ws_size,
                              hipStream_t stream) {
  const float* feat = (const float*)d_in[0];   // [4096, 256]
  const float* T    = (const float*)d_in[1];   // [2048, 65536]
  const float* W    = (const float*)d_in[2];   // [256, 2048]
  float* out = (float*)d_out;                  // [4096, 256]

  u16*   Km = (u16*)d_ws;                                        // 32 MB bf16 Kmat
  float* P  = (float*)((char*)d_ws + (size_t)DOUT * CDIM * 2);   // 32 MB partials

  k_wt <<<dim3(512),  dim3(512), 0, stream>>>(W, T, Km);
  k_bil<<<dim3(512),  dim3(512), 0, stream>>>(feat, Km, P);
  k_red<<<dim3(1024), dim3(256), 0, stream>>>(P, out);
}